// Round 4
// baseline (430.527 us; speedup 1.0000x reference)
//
#include <hip/hip_runtime.h>

// CANet fused kernel, round 9.
// Post-mortem r8: swizzle moved conflicts only 12.4M->10.3M. Derivation with
// counters: GEMM b128 B-reads are 16 rows x 4 col-chunks onto 8 bank windows
// -> >=4 distinct addrs/window under ANY row-only permutation; 1.83M reads x
// ~5.6 cyc == 10.3M. Dropping that chase (<=11% ceiling, mostly hidden).
// Real bottleneck per counters: per-SIMD VALU ~18%, MFMA ~5% -> barrier/
// latency stalls at 2.4 resident blocks/CU. r9 attacks residency + latency:
//  (1) LDS alias percS<->h2S (disjoint live ranges) into one 16KB buffer:
//      43.5K -> 34.7K LDS -> 4 blocks/CU; adds post-G3 barrier + per-iter
//      pad re-zero (G2 clobbers percS pad region).
//  (2) T14 tap prefetch: 27 conv global loads for it+1 issued end of conv(it),
//      land 3 barriers later; conv phase no longer L2-latency-bound. Raw
//      loads (clamped addrs), masks applied at consume.
//  (3) wpT[k][oc] transposed conv weights (prep does transpose): conv = 27
//      f32x4 FMAs (v_pk_fma) vs 108 scalar; bias f32x4; q-group broadcasts
//      hit disjoint bank quadrants by construction.

#define ACT_S 128     // 256 B rows, XOR-swizzled, for bufA/h1S [px][ch]
#define NOISE_BASE 9437184   // 16*9*65536

// d_ws: shorts [0,26624): w1b[128][64]@0, w2b[128][128]@8192, w3b[16][128]@24576
// floats @ WSF_OFF: bp[48], b1[128], b2[128], wpT[9][48], emb[48]
#define WSF_OFF 13312
#define WSF_BP 0
#define WSF_B1 48
#define WSF_B2 176
#define WSF_WP 304
#define WSF_EMB 736

typedef short bf16x8 __attribute__((ext_vector_type(8)));
typedef float f32x4 __attribute__((ext_vector_type(4)));

__device__ __forceinline__ short f2bf(float f) {
    union { float f; unsigned u; } cv; cv.f = f;
    unsigned r = cv.u + 0x7FFFu + ((cv.u >> 16) & 1u);
    return (short)(r >> 16);
}
// pack two fp32 -> dword of two bf16 (round-half-up): lo16=bf(f0), hi16=bf(f1)
__device__ __forceinline__ unsigned pk2bf(float f0, float f1) {
    union { float f; unsigned u; } a, b; a.f = f0; b.f = f1;
    return __builtin_amdgcn_perm(b.u + 0x8000u, a.u + 0x8000u, 0x07060302u);
}

// ---------------- weight prep + time embedding (one launch) ----------------
__global__ void prep_emb_kernel(const float* __restrict__ wpg, const float* __restrict__ bpg,
                                const float* __restrict__ w1g, const float* __restrict__ b1g,
                                const float* __restrict__ w2g, const float* __restrict__ b2g,
                                const float* __restrict__ w3g,
                                const int* __restrict__ t,
                                const float* __restrict__ wt, const float* __restrict__ bt,
                                short* __restrict__ wsb, float* __restrict__ wsf)
{
    if (blockIdx.x < 107) {
        int i = blockIdx.x * 256 + threadIdx.x;
        if (i < 8192) {                       // w1 [128][48] -> [128][64] pad
            int o = i >> 6, c = i & 63;
            wsb[i] = (c < 48) ? f2bf(w1g[o * 48 + c]) : (short)0;
        } else if (i < 24576) {               // w2 [128][128]
            wsb[i] = f2bf(w2g[i - 8192]);
        } else if (i < 26624) {               // w3 [12][128] -> [16][128] pad
            int k = i - 24576;
            wsb[i] = (k < 1536) ? f2bf(w3g[k]) : (short)0;
        } else if (i < 26672) {
            wsf[WSF_BP + (i - 26624)] = bpg[i - 26624];
        } else if (i < 26800) {
            wsf[WSF_B1 + (i - 26672)] = b1g[i - 26672];
        } else if (i < 26928) {
            wsf[WSF_B2 + (i - 26800)] = b2g[i - 26800];
        } else if (i < 27360) {
            int idx = i - 26928;              // wp transpose: [oc][k] -> [k][oc]
            int oc = idx / 9, k = idx % 9;
            wsf[WSF_WP + k * 48 + oc] = wpg[idx];
        }
        return;
    }
    int b = blockIdx.x - 107;
    int lane = threadIdx.x;
    if (lane >= 64) return;
    float tv = (float)t[b];
    float s0 = 0.f, s1 = 0.f, s2 = 0.f;
    const float LOG1E4 = 9.210340371976184f;
    #pragma unroll
    for (int ii = 0; ii < 2; ++ii) {
        int i = lane + ii * 64;
        float invf = __expf(-LOG1E4 * (float)i * (1.0f / 128.0f));
        float ang = tv * invf;
        float sn = sinf(ang), cs = cosf(ang);
        float ss = sn / (1.0f + __expf(-sn));
        float sc = cs / (1.0f + __expf(-cs));
        s0 += ss * wt[0 * 256 + i] + sc * wt[0 * 256 + i + 128];
        s1 += ss * wt[1 * 256 + i] + sc * wt[1 * 256 + i + 128];
        s2 += ss * wt[2 * 256 + i] + sc * wt[2 * 256 + i + 128];
    }
    #pragma unroll
    for (int off = 32; off; off >>= 1) {
        s0 += __shfl_down(s0, off);
        s1 += __shfl_down(s1, off);
        s2 += __shfl_down(s2, off);
    }
    if (lane == 0) {
        wsf[WSF_EMB + b * 3 + 0] = s0 + bt[0];
        wsf[WSF_EMB + b * 3 + 1] = s1 + bt[1];
        wsf[WSF_EMB + b * 3 + 2] = s2 + bt[2];
    }
}

// ---------------- main fused kernel ----------------
// MFMA 16x16x32 (m89): A lane(i=lane&15,q) holds A[i][q*8+j]; B symmetric:
// lane holds B[q*8+j][i]. D: col(N)=lane&15, row(M)=q*4+r.
// bufA timeline per iter: conv writes perc (cols 0..63) -> B1 -> G1 reads perc,
// writes h1S -> B2 -> G2 reads h1S, writes h2 (all 128 cols of bufA) -> B3 ->
// G3 reads bufA -> B4 -> next conv overwrites.
__global__ __launch_bounds__(256, 4) void canet_main(
    const float* __restrict__ xg,   // (16,3,256,256)
    const float* __restrict__ hg,   // (16,9,256,256)
    const short* __restrict__ wsb,
    const float* __restrict__ wsf,
    float* __restrict__ outg)
{
    __shared__ __align__(16) short bufA[64 * ACT_S];   // perc (cols<64) / h2
    __shared__ __align__(16) short h1S[64 * ACT_S];
    __shared__ __align__(16) float wpT_s[9 * 48];      // [k][oc]
    __shared__ float bp_s[48];

    const int tid = threadIdx.x;
    const int b = blockIdx.x >> 8;
    const int y = blockIdx.x & 255;

    for (int i = tid; i < 432; i += 256) wpT_s[i] = wsf[WSF_WP + i];
    if (tid < 48) bp_s[tid] = wsf[WSF_BP + tid];

    const int wv = tid >> 6;
    const int lane = tid & 63;
    const int m = lane & 15;
    const int q = lane >> 4;
    const int rsw = (m & 7) << 3;   // swizzle: every row this lane touches is == m (mod 16)

    // ---- weight fragments to registers (once per block) ----
    bf16x8 w1f[2][2], w2f[2][4], w3f[4];
    #pragma unroll
    for (int j = 0; j < 2; ++j) {
        int n = wv * 32 + j * 16 + m;
        #pragma unroll
        for (int ks = 0; ks < 2; ++ks)
            w1f[j][ks] = *(const bf16x8*)(wsb + n * 64 + ks * 32 + q * 8);
        #pragma unroll
        for (int ks = 0; ks < 4; ++ks)
            w2f[j][ks] = *(const bf16x8*)(wsb + 8192 + n * 128 + ks * 32 + q * 8);
    }
    #pragma unroll
    for (int ks = 0; ks < 4; ++ks)
        w3f[ks] = *(const bf16x8*)(wsb + 24576 + m * 128 + ks * 32 + q * 8);

    // bias vectors: D rows = channels (wv*32 + j*16 + q*4 + r)
    f32x4 b1v[2], b2v[2];
    #pragma unroll
    for (int j = 0; j < 2; ++j) {
        b1v[j] = *(const f32x4*)(wsf + WSF_B1 + wv * 32 + j * 16 + q * 4);
        b2v[j] = *(const f32x4*)(wsf + WSF_B2 + wv * 32 + j * 16 + q * 4);
    }
    const float embv = (m < 3) ? wsf[WSF_EMB + b * 3 + m] : 0.0f;

    // conv source pointers (lane's 3 input channels: ic = 3q + i3)
    const float* src3[3];
    #pragma unroll
    for (int i3 = 0; i3 < 3; ++i3) {
        int ic = 3 * q + i3;
        src3[i3] = (ic < 3) ? (xg + (((size_t)b * 3 + ic) << 16))
                            : (hg + (((size_t)b * 9 + (ic - 3)) << 16));
    }
    // clamped y-row offsets + validity (uniform per block)
    int yoff[3]; bool yokk[3];
    #pragma unroll
    for (int ky = 0; ky < 3; ++ky) {
        int yy = y + ky - 1;
        yokk[ky] = (yy >= 0) && (yy < 256);
        yoff[ky] = (yokk[ky] ? yy : y) * 256;
    }

    // raw (unmasked, addr-clamped) tap loads for pixel pxl into tp[27]
    auto load_taps = [&](float (&tp)[27], int pxl) {
        const int xm1 = pxl - (pxl > 0);
        const int xp1 = pxl + (pxl < 255);
        #pragma unroll
        for (int i3 = 0; i3 < 3; ++i3) {
            #pragma unroll
            for (int ky = 0; ky < 3; ++ky) {
                const float* rp = src3[i3] + yoff[ky];
                tp[i3 * 9 + ky * 3 + 0] = rp[xm1];
                tp[i3 * 9 + ky * 3 + 1] = rp[pxl];
                tp[i3 * 9 + ky * 3 + 2] = rp[xp1];
            }
        }
    };

    float tp[27];
    load_taps(tp, wv * 16 + m);     // it=0 prefetch (global only, pre-barrier ok)

    __syncthreads();   // wpT_s/bp_s ready

    for (int it = 0; it < 4; ++it) {
        const int x0 = it * 64;
        const int px = x0 + wv * 16 + m;

        // ---- depthwise 3x3 conv -> bufA[px][ch<48] (swizzled cols) ----
        {
            const bool okl = (px > 0), okr = (px < 255);
            // mask prefetched taps (frees tp for next prefetch)
            float tm[27];
            #pragma unroll
            for (int i3 = 0; i3 < 3; ++i3) {
                #pragma unroll
                for (int ky = 0; ky < 3; ++ky) {
                    int o = i3 * 9 + ky * 3;
                    tm[o + 0] = (yokk[ky] && okl) ? tp[o + 0] : 0.0f;
                    tm[o + 1] = yokk[ky] ? tp[o + 1] : 0.0f;
                    tm[o + 2] = (yokk[ky] && okr) ? tp[o + 2] : 0.0f;
                }
            }
            // prefetch next iter's taps now; they land ~3 barriers later
            if (it < 3) load_taps(tp, px + 64);

            short* prow = bufA + (wv * 16 + m) * ACT_S;
            #pragma unroll
            for (int i3 = 0; i3 < 3; ++i3) {
                f32x4 acc = *(const f32x4*)(bp_s + 12 * q + 4 * i3);
                #pragma unroll
                for (int k = 0; k < 9; ++k) {
                    f32x4 w4 = *(const f32x4*)(wpT_s + k * 48 + 12 * q + 4 * i3);
                    float t = tm[i3 * 9 + k];
                    acc[0] += w4[0] * t; acc[1] += w4[1] * t;
                    acc[2] += w4[2] * t; acc[3] += w4[3] * t;
                }
                uint2 pk;
                pk.x = pk2bf(acc[0], acc[1]);
                pk.y = pk2bf(acc[2], acc[3]);
                *(uint2*)(prow + ((12 * q + 4 * i3) ^ rsw)) = pk;
            }
            // K pad (orig cols 48..63): re-zero every iter (G2 clobbers bufA)
            *(uint2*)(prow + ((48 + 4 * q) ^ rsw)) = uint2{0u, 0u};
        }
        __syncthreads();   // B1: perc ready

        // ---- GEMM1 (swapped): D[ch][px] = w1 . perc^T ; write h1S[px][ch] ----
        #pragma unroll
        for (int nt = 0; nt < 4; ++nt) {
            f32x4 c0 = b1v[0], c1 = b1v[1];
            #pragma unroll
            for (int ks = 0; ks < 2; ++ks) {
                bf16x8 p = *(const bf16x8*)(bufA + (nt * 16 + m) * ACT_S + ((ks * 32 + q * 8) ^ rsw));
                c0 = __builtin_amdgcn_mfma_f32_16x16x32_bf16(w1f[0][ks], p, c0, 0, 0, 0);
                c1 = __builtin_amdgcn_mfma_f32_16x16x32_bf16(w1f[1][ks], p, c1, 0, 0, 0);
            }
            short* drow = h1S + (nt * 16 + m) * ACT_S;
            uint2 pk;
            pk.x = pk2bf(fmaxf(c0[0], 0.f), fmaxf(c0[1], 0.f));
            pk.y = pk2bf(fmaxf(c0[2], 0.f), fmaxf(c0[3], 0.f));
            *(uint2*)(drow + ((wv * 32 + q * 4) ^ rsw)) = pk;
            pk.x = pk2bf(fmaxf(c1[0], 0.f), fmaxf(c1[1], 0.f));
            pk.y = pk2bf(fmaxf(c1[2], 0.f), fmaxf(c1[3], 0.f));
            *(uint2*)(drow + ((wv * 32 + q * 4 + 16) ^ rsw)) = pk;
        }
        __syncthreads();   // B2: h1 ready; perc fully read

        // ---- GEMM2 (swapped): D[ch][px] = w2 . h1^T ; write h2 -> bufA ----
        #pragma unroll
        for (int nt = 0; nt < 4; ++nt) {
            f32x4 c0 = b2v[0], c1 = b2v[1];
            #pragma unroll
            for (int ks = 0; ks < 4; ++ks) {
                bf16x8 a = *(const bf16x8*)(h1S + (nt * 16 + m) * ACT_S + ((ks * 32 + q * 8) ^ rsw));
                c0 = __builtin_amdgcn_mfma_f32_16x16x32_bf16(w2f[0][ks], a, c0, 0, 0, 0);
                c1 = __builtin_amdgcn_mfma_f32_16x16x32_bf16(w2f[1][ks], a, c1, 0, 0, 0);
            }
            short* drow = bufA + (nt * 16 + m) * ACT_S;
            uint2 pk;
            pk.x = pk2bf(fmaxf(c0[0], 0.f), fmaxf(c0[1], 0.f));
            pk.y = pk2bf(fmaxf(c0[2], 0.f), fmaxf(c0[3], 0.f));
            *(uint2*)(drow + ((wv * 32 + q * 4) ^ rsw)) = pk;
            pk.x = pk2bf(fmaxf(c1[0], 0.f), fmaxf(c1[1], 0.f));
            pk.y = pk2bf(fmaxf(c1[2], 0.f), fmaxf(c1[3], 0.f));
            *(uint2*)(drow + ((wv * 32 + q * 4 + 16) ^ rsw)) = pk;
        }
        __syncthreads();   // B3: h2 ready

        // ---- GEMM3: out = h2 . w3^T ; D col=oc, row=px; float4 store ----
        {
            f32x4 acc = {0.f, 0.f, 0.f, 0.f};
            #pragma unroll
            for (int ks = 0; ks < 4; ++ks) {
                bf16x8 a = *(const bf16x8*)(bufA + (wv * 16 + m) * ACT_S + ((ks * 32 + q * 8) ^ rsw));
                acc = __builtin_amdgcn_mfma_f32_16x16x32_bf16(a, w3f[ks], acc, 0, 0, 0);
            }
            if (m < 12) {
                int xx0 = x0 + wv * 16 + q * 4;
                size_t idx;
                if (m < 3) {
                    idx = (size_t)NOISE_BASE + (((size_t)b * 3 + m) << 16) + (size_t)y * 256 + xx0;
                } else {
                    idx = (((size_t)b * 9 + (m - 3)) << 16) + (size_t)y * 256 + xx0;
                }
                f32x4 vst = {acc[0] + embv, acc[1] + embv, acc[2] + embv, acc[3] + embv};
                *(f32x4*)(outg + idx) = vst;
            }
        }
        __syncthreads();   // B4: bufA fully read; next conv may overwrite
    }
}

extern "C" void kernel_launch(void* const* d_in, const int* in_sizes, int n_in,
                              void* d_out, int out_size, void* d_ws, size_t ws_size,
                              hipStream_t stream) {
    const float* xg  = (const float*)d_in[0];
    const float* hg  = (const float*)d_in[1];
    const int*   tg  = (const int*)  d_in[2];
    const float* wpg = (const float*)d_in[3];
    const float* bpg = (const float*)d_in[4];
    const float* w1g = (const float*)d_in[5];
    const float* b1g = (const float*)d_in[6];
    const float* w2g = (const float*)d_in[7];
    const float* b2g = (const float*)d_in[8];
    const float* w3g = (const float*)d_in[9];
    const float* wtg = (const float*)d_in[10];
    const float* btg = (const float*)d_in[11];
    float* outg = (float*)d_out;
    short* wsb  = (short*)d_ws;
    float* wsf  = (float*)d_ws + WSF_OFF;

    prep_emb_kernel<<<123, 256, 0, stream>>>(wpg, bpg, w1g, b1g, w2g, b2g, w3g,
                                             tg, wtg, btg, wsb, wsf);
    canet_main<<<4096, 256, 0, stream>>>(xg, hg, wsb, wsf, outg);
}

// Round 5
// 224.647 us; speedup vs baseline: 1.9165x; 1.9165x over previous
//
#include <hip/hip_runtime.h>

// CANet fused kernel, round 10.
// Post-mortem r9: launch_bounds(256,4) + tap-prefetch (+54 live regs) forced
// VGPR 84->64 -> full spill (FETCH 603MB, WRITE 450MB scratch traffic, 348us).
// Lesson: register budget is tight at 84; occupancy gains must hold VGPR flat.
// r10 = r5 (best, 139us) + ONE change: alias percS<->h2S into bufA[64][136].
//  - perc lives cols 0..63 of bufA rows (272B stride == 4 dwords mod 32 banks,
//    identical bank stagger to r5's 144B percS rows).
//  - LDS 46.6K -> 37.4K -> 4 blocks/CU (84 VGPR supports 4 blocks at the
//    128-reg granularity step). Adds barrier B4 (G3 must finish reading bufA
//    before next iter's conv overwrites it).
//  - Everything else byte-identical to r5: no prefetch, launch_bounds(256,3),
//    same conv fast path, same wp_s skew, same per-iter pad zeroing.

#define ACT_S 136     // 272 B rows (16B-aligned) for bufA/h1S [px][ch]
#define NOISE_BASE 9437184   // 16*9*65536

// d_ws: shorts [0,26624): w1b[128][64]@0, w2b[128][128]@8192, w3b[16][128]@24576
// floats @ WSF_OFF: bp[48], b1[128], b2[128], wp[432], emb[48]
#define WSF_OFF 13312
#define WSF_BP 0
#define WSF_B1 48
#define WSF_B2 176
#define WSF_WP 304
#define WSF_EMB 736

typedef short bf16x8 __attribute__((ext_vector_type(8)));
typedef float f32x4 __attribute__((ext_vector_type(4)));

__device__ __forceinline__ short f2bf(float f) {
    union { float f; unsigned u; } cv; cv.f = f;
    unsigned r = cv.u + 0x7FFFu + ((cv.u >> 16) & 1u);
    return (short)(r >> 16);
}
// pack two fp32 -> dword of two bf16 (round-half-up): lo16=bf(f0), hi16=bf(f1)
__device__ __forceinline__ unsigned pk2bf(float f0, float f1) {
    union { float f; unsigned u; } a, b; a.f = f0; b.f = f1;
    return __builtin_amdgcn_perm(b.u + 0x8000u, a.u + 0x8000u, 0x07060302u);
}

// ---------------- weight prep + time embedding (one launch) ----------------
__global__ void prep_emb_kernel(const float* __restrict__ wpg, const float* __restrict__ bpg,
                                const float* __restrict__ w1g, const float* __restrict__ b1g,
                                const float* __restrict__ w2g, const float* __restrict__ b2g,
                                const float* __restrict__ w3g,
                                const int* __restrict__ t,
                                const float* __restrict__ wt, const float* __restrict__ bt,
                                short* __restrict__ wsb, float* __restrict__ wsf)
{
    if (blockIdx.x < 107) {
        int i = blockIdx.x * 256 + threadIdx.x;
        if (i < 8192) {                       // w1 [128][48] -> [128][64] pad
            int o = i >> 6, c = i & 63;
            wsb[i] = (c < 48) ? f2bf(w1g[o * 48 + c]) : (short)0;
        } else if (i < 24576) {               // w2 [128][128]
            wsb[i] = f2bf(w2g[i - 8192]);
        } else if (i < 26624) {               // w3 [12][128] -> [16][128] pad
            int k = i - 24576;
            wsb[i] = (k < 1536) ? f2bf(w3g[k]) : (short)0;
        } else if (i < 26672) {
            wsf[WSF_BP + (i - 26624)] = bpg[i - 26624];
        } else if (i < 26800) {
            wsf[WSF_B1 + (i - 26672)] = b1g[i - 26672];
        } else if (i < 26928) {
            wsf[WSF_B2 + (i - 26800)] = b2g[i - 26800];
        } else if (i < 27360) {
            wsf[WSF_WP + (i - 26928)] = wpg[i - 26928];
        }
        return;
    }
    int b = blockIdx.x - 107;
    int lane = threadIdx.x;
    if (lane >= 64) return;
    float tv = (float)t[b];
    float s0 = 0.f, s1 = 0.f, s2 = 0.f;
    const float LOG1E4 = 9.210340371976184f;
    #pragma unroll
    for (int ii = 0; ii < 2; ++ii) {
        int i = lane + ii * 64;
        float invf = __expf(-LOG1E4 * (float)i * (1.0f / 128.0f));
        float ang = tv * invf;
        float sn = sinf(ang), cs = cosf(ang);
        float ss = sn / (1.0f + __expf(-sn));
        float sc = cs / (1.0f + __expf(-cs));
        s0 += ss * wt[0 * 256 + i] + sc * wt[0 * 256 + i + 128];
        s1 += ss * wt[1 * 256 + i] + sc * wt[1 * 256 + i + 128];
        s2 += ss * wt[2 * 256 + i] + sc * wt[2 * 256 + i + 128];
    }
    #pragma unroll
    for (int off = 32; off; off >>= 1) {
        s0 += __shfl_down(s0, off);
        s1 += __shfl_down(s1, off);
        s2 += __shfl_down(s2, off);
    }
    if (lane == 0) {
        wsf[WSF_EMB + b * 3 + 0] = s0 + bt[0];
        wsf[WSF_EMB + b * 3 + 1] = s1 + bt[1];
        wsf[WSF_EMB + b * 3 + 2] = s2 + bt[2];
    }
}

// ---------------- main fused kernel ----------------
// MFMA 16x16x32 (m89): A lane(i=lane&15,q) holds A[i][q*8+j]; B symmetric:
// lane holds B[q*8+j][i]. D: col(N)=lane&15, row(M)=q*4+r.
// bufA timeline per iter: conv writes perc (cols 0..63) -> B1 -> G1 reads perc,
// writes h1S -> B2 -> G2 reads h1S, writes h2 (cols 0..127 of bufA) -> B3 ->
// G3 reads bufA -> B4 -> next iter's conv overwrites bufA.
__global__ __launch_bounds__(256, 3) void canet_main(
    const float* __restrict__ xg,   // (16,3,256,256)
    const float* __restrict__ hg,   // (16,9,256,256)
    const short* __restrict__ wsb,
    const float* __restrict__ wsf,
    float* __restrict__ outg)
{
    __shared__ __align__(16) short bufA[64 * ACT_S];   // perc (cols<64) / h2
    __shared__ __align__(16) short h1S[64 * ACT_S];
    __shared__ __align__(16) float wp_s[48 * 12];   // 9 taps padded to 12
    __shared__ float bp_s[48];

    const int tid = threadIdx.x;
    const int b = blockIdx.x >> 8;
    const int y = blockIdx.x & 255;

    for (int i = tid; i < 576; i += 256) {
        int oc = i / 12, k = i % 12;
        wp_s[i] = (k < 9) ? wsf[WSF_WP + oc * 9 + k] : 0.0f;
    }
    if (tid < 48) bp_s[tid] = wsf[WSF_BP + tid];

    const int wv = tid >> 6;
    const int lane = tid & 63;
    const int m = lane & 15;
    const int q = lane >> 4;

    // ---- weight fragments to registers (once per block) ----
    bf16x8 w1f[2][2], w2f[2][4], w3f[4];
    #pragma unroll
    for (int j = 0; j < 2; ++j) {
        int n = wv * 32 + j * 16 + m;
        #pragma unroll
        for (int ks = 0; ks < 2; ++ks)
            w1f[j][ks] = *(const bf16x8*)(wsb + n * 64 + ks * 32 + q * 8);
        #pragma unroll
        for (int ks = 0; ks < 4; ++ks)
            w2f[j][ks] = *(const bf16x8*)(wsb + 8192 + n * 128 + ks * 32 + q * 8);
    }
    #pragma unroll
    for (int ks = 0; ks < 4; ++ks)
        w3f[ks] = *(const bf16x8*)(wsb + 24576 + m * 128 + ks * 32 + q * 8);

    // bias vectors: D rows = channels (wv*32 + j*16 + q*4 + r)
    f32x4 b1v[2], b2v[2];
    #pragma unroll
    for (int j = 0; j < 2; ++j) {
        b1v[j] = *(const f32x4*)(wsf + WSF_B1 + wv * 32 + j * 16 + q * 4);
        b2v[j] = *(const f32x4*)(wsf + WSF_B2 + wv * 32 + j * 16 + q * 4);
    }
    const float embv = (m < 3) ? wsf[WSF_EMB + b * 3 + m] : 0.0f;

    // conv source pointers (lane's 3 input channels: ic = 3q + i3)
    const float* src3[3];
    #pragma unroll
    for (int i3 = 0; i3 < 3; ++i3) {
        int ic = 3 * q + i3;
        src3[i3] = (ic < 3) ? (xg + (((size_t)b * 3 + ic) << 16))
                            : (hg + (((size_t)b * 9 + (ic - 3)) << 16));
    }

    __syncthreads();   // wp_s/bp_s ready

    for (int it = 0; it < 4; ++it) {
        const int x0 = it * 64;
        const int px = x0 + wv * 16 + m;

        // ---- depthwise 3x3 conv -> bufA[px][ch<48] + pad ----
        {
            const int xm1 = px - (px > 0);
            const int xp1 = px + (px < 255);
            const bool okl = (px > 0), okr = (px < 255);
            short* prow = bufA + (wv * 16 + m) * ACT_S;
            const bool interior = (y >= 1) && (y <= 254);
            #pragma unroll
            for (int i3 = 0; i3 < 3; ++i3) {
                const float* s = src3[i3];
                float tap[9];
                if (interior) {
                    #pragma unroll
                    for (int ky = 0; ky < 3; ++ky) {
                        const float* rp = s + (y + ky - 1) * 256;
                        float c0 = rp[xm1], c1 = rp[px], c2 = rp[xp1];
                        tap[ky * 3 + 0] = okl ? c0 : 0.0f;
                        tap[ky * 3 + 1] = c1;
                        tap[ky * 3 + 2] = okr ? c2 : 0.0f;
                    }
                } else {
                    #pragma unroll
                    for (int ky = 0; ky < 3; ++ky) {
                        int yy = y + ky - 1;
                        bool yok = (yy >= 0) && (yy < 256);
                        const float* rp = s + (yok ? yy : y) * 256;
                        float c0 = rp[xm1], c1 = rp[px], c2 = rp[xp1];
                        tap[ky * 3 + 0] = (yok && okl) ? c0 : 0.0f;
                        tap[ky * 3 + 1] = yok ? c1 : 0.0f;
                        tap[ky * 3 + 2] = (yok && okr) ? c2 : 0.0f;
                    }
                }
                float v[4];
                #pragma unroll
                for (int r = 0; r < 4; ++r) {
                    int oc = 12 * q + 4 * i3 + r;
                    const float* wrow = &wp_s[oc * 12];
                    f32x4 w0 = *(const f32x4*)wrow;
                    f32x4 w1_ = *(const f32x4*)(wrow + 4);
                    float a = bp_s[oc];
                    a += w0[0] * tap[0] + w0[1] * tap[1] + w0[2] * tap[2] + w0[3] * tap[3];
                    a += w1_[0] * tap[4] + w1_[1] * tap[5] + w1_[2] * tap[6] + w1_[3] * tap[7];
                    a += wrow[8] * tap[8];
                    v[r] = a;
                }
                uint2 pk;
                pk.x = pk2bf(v[0], v[1]);
                pk.y = pk2bf(v[2], v[3]);
                *(uint2*)(prow + 12 * q + 4 * i3) = pk;
            }
            *(uint2*)(prow + 48 + 4 * q) = uint2{0u, 0u};   // K pad 48..63 (G2 clobbers)
        }
        __syncthreads();   // B1: perc ready

        // ---- GEMM1 (swapped): D[ch][px] = w1 . perc^T ; write h1S[px][ch] ----
        #pragma unroll
        for (int nt = 0; nt < 4; ++nt) {
            f32x4 c0 = b1v[0], c1 = b1v[1];
            #pragma unroll
            for (int ks = 0; ks < 2; ++ks) {
                bf16x8 p = *(const bf16x8*)(bufA + (nt * 16 + m) * ACT_S + ks * 32 + q * 8);
                c0 = __builtin_amdgcn_mfma_f32_16x16x32_bf16(w1f[0][ks], p, c0, 0, 0, 0);
                c1 = __builtin_amdgcn_mfma_f32_16x16x32_bf16(w1f[1][ks], p, c1, 0, 0, 0);
            }
            short* drow = h1S + (nt * 16 + m) * ACT_S + wv * 32 + q * 4;
            uint2 pk;
            pk.x = pk2bf(fmaxf(c0[0], 0.f), fmaxf(c0[1], 0.f));
            pk.y = pk2bf(fmaxf(c0[2], 0.f), fmaxf(c0[3], 0.f));
            *(uint2*)drow = pk;
            pk.x = pk2bf(fmaxf(c1[0], 0.f), fmaxf(c1[1], 0.f));
            pk.y = pk2bf(fmaxf(c1[2], 0.f), fmaxf(c1[3], 0.f));
            *(uint2*)(drow + 16) = pk;
        }
        __syncthreads();   // B2: h1 ready; perc fully read

        // ---- GEMM2 (swapped): D[ch][px] = w2 . h1^T ; write h2 -> bufA ----
        #pragma unroll
        for (int nt = 0; nt < 4; ++nt) {
            f32x4 c0 = b2v[0], c1 = b2v[1];
            #pragma unroll
            for (int ks = 0; ks < 4; ++ks) {
                bf16x8 a = *(const bf16x8*)(h1S + (nt * 16 + m) * ACT_S + ks * 32 + q * 8);
                c0 = __builtin_amdgcn_mfma_f32_16x16x32_bf16(w2f[0][ks], a, c0, 0, 0, 0);
                c1 = __builtin_amdgcn_mfma_f32_16x16x32_bf16(w2f[1][ks], a, c1, 0, 0, 0);
            }
            short* drow = bufA + (nt * 16 + m) * ACT_S + wv * 32 + q * 4;
            uint2 pk;
            pk.x = pk2bf(fmaxf(c0[0], 0.f), fmaxf(c0[1], 0.f));
            pk.y = pk2bf(fmaxf(c0[2], 0.f), fmaxf(c0[3], 0.f));
            *(uint2*)drow = pk;
            pk.x = pk2bf(fmaxf(c1[0], 0.f), fmaxf(c1[1], 0.f));
            pk.y = pk2bf(fmaxf(c1[2], 0.f), fmaxf(c1[3], 0.f));
            *(uint2*)(drow + 16) = pk;
        }
        __syncthreads();   // B3: h2 ready

        // ---- GEMM3: out = h2 . w3^T ; D col=oc, row=px; float4 store ----
        {
            f32x4 acc = {0.f, 0.f, 0.f, 0.f};
            #pragma unroll
            for (int ks = 0; ks < 4; ++ks) {
                bf16x8 a = *(const bf16x8*)(bufA + (wv * 16 + m) * ACT_S + ks * 32 + q * 8);
                acc = __builtin_amdgcn_mfma_f32_16x16x32_bf16(a, w3f[ks], acc, 0, 0, 0);
            }
            if (m < 12) {
                int xx0 = x0 + wv * 16 + q * 4;
                size_t idx;
                if (m < 3) {
                    idx = (size_t)NOISE_BASE + (((size_t)b * 3 + m) << 16) + (size_t)y * 256 + xx0;
                } else {
                    idx = (((size_t)b * 9 + (m - 3)) << 16) + (size_t)y * 256 + xx0;
                }
                f32x4 vst = {acc[0] + embv, acc[1] + embv, acc[2] + embv, acc[3] + embv};
                *(f32x4*)(outg + idx) = vst;
            }
        }
        __syncthreads();   // B4: bufA fully read; next conv may overwrite
    }
}

extern "C" void kernel_launch(void* const* d_in, const int* in_sizes, int n_in,
                              void* d_out, int out_size, void* d_ws, size_t ws_size,
                              hipStream_t stream) {
    const float* xg  = (const float*)d_in[0];
    const float* hg  = (const float*)d_in[1];
    const int*   tg  = (const int*)  d_in[2];
    const float* wpg = (const float*)d_in[3];
    const float* bpg = (const float*)d_in[4];
    const float* w1g = (const float*)d_in[5];
    const float* b1g = (const float*)d_in[6];
    const float* w2g = (const float*)d_in[7];
    const float* b2g = (const float*)d_in[8];
    const float* w3g = (const float*)d_in[9];
    const float* wtg = (const float*)d_in[10];
    const float* btg = (const float*)d_in[11];
    float* outg = (float*)d_out;
    short* wsb  = (short*)d_ws;
    float* wsf  = (float*)d_ws + WSF_OFF;

    prep_emb_kernel<<<123, 256, 0, stream>>>(wpg, bpg, w1g, b1g, w2g, b2g, w3g,
                                             tg, wtg, btg, wsb, wsf);
    canet_main<<<4096, 256, 0, stream>>>(xg, hg, wsb, wsf, outg);
}